// Round 10
// baseline (64.586 us; speedup 1.0000x reference)
//
#include <hip/hip_runtime.h>
#include <cmath>

typedef _Float16 half8 __attribute__((ext_vector_type(8)));
typedef float f32x4 __attribute__((ext_vector_type(4)));

constexpr int D    = 512;
constexpr int NC   = 225;   // classes
constexpr int NPC  = 224;   // outputs per class
constexpr int N1   = 256;   // padded W1 cols
constexpr int TB   = 32;    // tokens per chunk
constexpr int LST  = 260;   // logits LDS row stride (f32)

// ws layout (int units)
constexpr int WS_NCHUNK = 0;
constexpr int WS_CHUNK  = 16;                      // 481*4 ints (cls,start,cnt,0)
constexpr int WS_ORDER  = 4096;                    // 4096 ids grouped by class
constexpr int WS_P1     = 8192;                    // 4096 floats
constexpr int WS_P2     = 12288;                   // 4096 floats
constexpr int WS_B1P    = 16384;                   // 256 floats padded b1
constexpr int WS_W1H    = 16640;                   // 256*512 halves (transposed [col][k])
constexpr int WS_W1L    = WS_W1H + 65536;
constexpr int WS_XH     = WS_W1L + 65536;          // 4096*512 halves
constexpr int WS_XL     = WS_XH + 1048576;         // 4096*512 halves

// ---------- prep: histogram + scans + chunk table (p2 first) + scatter ----------
__global__ __launch_bounds__(256) void k_prep(const int* __restrict__ target,
                                              int* __restrict__ ws, int ntok) {
    __shared__ int h[256], sc[256], sc2[256], cur[NC];
    const int tid = threadIdx.x;
    h[tid] = 0;
    __syncthreads();
    for (int n = tid; n < ntok; n += 256) atomicAdd(&h[target[n] / NPC], 1);
    __syncthreads();
    const int hv = h[tid];
    sc[tid] = hv; __syncthreads();
    for (int o = 1; o < 256; o <<= 1) {
        int a = (tid >= o) ? sc[tid - o] : 0;
        __syncthreads();
        sc[tid] += a;
        __syncthreads();
    }
    const int start = sc[tid] - hv;
    const int nch = (tid < NC) ? (hv + TB - 1) / TB : 0;
    sc2[tid] = nch; __syncthreads();
    for (int o = 1; o < 256; o <<= 1) {
        int a = (tid >= o) ? sc2[tid - o] : 0;
        __syncthreads();
        sc2[tid] += a;
        __syncthreads();
    }
    const int nch2 = sc2[255];
    if (tid < NC) {
        cur[tid] = start;
        const int cb = sc2[tid] - nch;
        for (int j = 0; j < nch; ++j) {
            const int e = WS_CHUNK + (cb + j) * 4;
            ws[e + 0] = tid;
            ws[e + 1] = start + j * TB;
            ws[e + 2] = min(TB, hv - j * TB);
            ws[e + 3] = 0;
        }
    }
    const int P1C = ntok / TB;      // 128
    if (tid < P1C) {
        const int e = WS_CHUNK + (nch2 + tid) * 4;
        ws[e + 0] = -1;
        ws[e + 1] = tid * TB;
        ws[e + 2] = TB;
        ws[e + 3] = 0;
    }
    if (tid == 0) ws[WS_NCHUNK] = nch2 + P1C;
    __syncthreads();
    for (int n = tid; n < ntok; n += 256) {
        const int c = target[n] / NPC;
        const int pos = atomicAdd(&cur[c], 1);
        ws[WS_ORDER + pos] = n;
    }
}

// fp16 split: hi = RTN(v), flushed to 0 if subnormal; lo = RTN((v-hi)*2048)
__device__ __forceinline__ void f16split(float v, _Float16& h, _Float16& l) {
    _Float16 hh = (_Float16)v;
    float hf = (float)hh;
    if (fabsf(hf) < 6.104e-5f) { hh = (_Float16)0.f; hf = 0.f; }
    h = hh;
    l = (_Float16)((v - hf) * 2048.0f);
}

// ---------- pre-pass: convert x (h/l), transpose-convert W1, pad b1 ----------
__global__ __launch_bounds__(256) void k_pre(const float* __restrict__ x,
                                             const float* __restrict__ W1,
                                             const float* __restrict__ b1,
                                             int* __restrict__ ws, int ntok) {
    const int bid = blockIdx.x, tid = threadIdx.x;
    _Float16* xh  = (_Float16*)(ws + WS_XH);
    _Float16* xl  = (_Float16*)(ws + WS_XL);
    _Float16* w1h = (_Float16*)(ws + WS_W1H);
    _Float16* w1l = (_Float16*)(ws + WS_W1L);
    const int XBLK = (ntok * D) / (256 * 8);           // 1024
    if (bid < XBLK) {
        const int base = (bid * 256 + tid) * 8;
        const float4 a = *(const float4*)(x + base);
        const float4 b = *(const float4*)(x + base + 4);
        const float v[8] = {a.x, a.y, a.z, a.w, b.x, b.y, b.z, b.w};
        half8 hv, lv;
        #pragma unroll
        for (int j = 0; j < 8; ++j) {
            _Float16 hq, lq;
            f16split(v[j], hq, lq);
            hv[j] = hq; lv[j] = lq;
        }
        *(half8*)(xh + base) = hv;
        *(half8*)(xl + base) = lv;
    } else if (bid < XBLK + 64) {
        const int oi = ((bid - XBLK) * 256 + tid) * 8;  // [c][k], 8 k each
        const int c = oi >> 9, k0 = oi & 511;
        half8 hv, lv;
        #pragma unroll
        for (int j = 0; j < 8; ++j) {
            const float v = (c < NC) ? W1[(size_t)(k0 + j) * NC + c] : 0.f;
            _Float16 hq, lq;
            f16split(v, hq, lq);
            hv[j] = hq; lv[j] = lq;
        }
        *(half8*)(w1h + oi) = hv;
        *(half8*)(w1l + oi) = lv;
    } else {
        float* b1p = (float*)ws + WS_B1P;
        if (tid < N1) b1p[tid] = (tid < NC) ? b1[tid] : 0.f;
    }
}

// ---------- main: barrier-free K-loop, fp16-split MFMA ----------
template <bool PH2>
__device__ __forceinline__ void run_chunk(
    const int* __restrict__ target,
    const float* __restrict__ W2c, const float* __restrict__ bsrc,
    const _Float16* __restrict__ w1h, const _Float16* __restrict__ w1l,
    const _Float16* __restrict__ xh, const _Float16* __restrict__ xl,
    int* __restrict__ ws, float* __restrict__ ls, int* __restrict__ stok,
    int start, int cnt)
{
    constexpr int NREAL = PH2 ? NPC : NC;
    const int tid  = threadIdx.x;
    const int w    = tid >> 6;
    const int lane = tid & 63;
    const int l15  = lane & 15, l4 = lane >> 4;

    if (tid < TB)
        stok[tid] = PH2 ? ws[WS_ORDER + start + min(tid, cnt - 1)] : (start + tid);
    __syncthreads();

    const int ntiles = PH2 ? ((cnt + 15) >> 4) : 2;
    int xoff[2];
    xoff[0] = stok[l15] * D;
    xoff[1] = stok[16 + l15] * D;

    f32x4 accA[4][2] = {};   // hi*hi
    f32x4 accB[4][2] = {};   // cross terms (scaled x2048)

    for (int k0 = 0; k0 < D; k0 += 32) {
        // B fragments from pre-converted x (16B aligned, L2-resident)
        half8 Bh[2], Bl[2];
        #pragma unroll
        for (int n = 0; n < 2; ++n) {
            if (n < ntiles) {
                Bh[n] = *(const half8*)(xh + xoff[n] + k0 + l4 * 8);
                Bl[n] = *(const half8*)(xl + xoff[n] + k0 + l4 * 8);
            }
        }
        if (PH2) {
            // hoist all 32 W2 scalar loads (coalesced 64B/16-lane segments)
            float wr[4][8];
            #pragma unroll
            for (int mi = 0; mi < 4; ++mi) {
                const int col = ((((7 * w) >> 1) + mi) * 16) + l15;
                const float* wp = W2c + (size_t)(k0 + l4 * 8) * NPC + col;
                #pragma unroll
                for (int j = 0; j < 8; ++j) wr[mi][j] = wp[(size_t)j * NPC];
            }
            #pragma unroll
            for (int mi = 0; mi < 4; ++mi) {
                half8 Ah, Al;
                #pragma unroll
                for (int j = 0; j < 8; ++j) {
                    _Float16 hq, lq;
                    f16split(wr[mi][j], hq, lq);
                    Ah[j] = hq; Al[j] = lq;
                }
                const int m = ((7 * w) >> 1) + mi;
                #pragma unroll
                for (int n = 0; n < 2; ++n) {
                    const int ct = 2 * m + n;
                    if (ct >= 7 * w && ct < 7 * w + 7 && n < ntiles) {
                        accA[mi][n] = __builtin_amdgcn_mfma_f32_16x16x32_f16(Ah, Bh[n], accA[mi][n], 0, 0, 0);
                        accB[mi][n] = __builtin_amdgcn_mfma_f32_16x16x32_f16(Ah, Bl[n], accB[mi][n], 0, 0, 0);
                        accB[mi][n] = __builtin_amdgcn_mfma_f32_16x16x32_f16(Al, Bh[n], accB[mi][n], 0, 0, 0);
                    }
                }
            }
        } else {
            #pragma unroll
            for (int mi = 0; mi < 4; ++mi) {
                const int col = (4 * w + mi) * 16 + l15;
                const half8 Ah = *(const half8*)(w1h + (size_t)col * D + k0 + l4 * 8);
                const half8 Al = *(const half8*)(w1l + (size_t)col * D + k0 + l4 * 8);
                #pragma unroll
                for (int n = 0; n < 2; ++n) {
                    accA[mi][n] = __builtin_amdgcn_mfma_f32_16x16x32_f16(Ah, Bh[n], accA[mi][n], 0, 0, 0);
                    accB[mi][n] = __builtin_amdgcn_mfma_f32_16x16x32_f16(Ah, Bl[n], accB[mi][n], 0, 0, 0);
                    accB[mi][n] = __builtin_amdgcn_mfma_f32_16x16x32_f16(Al, Bh[n], accB[mi][n], 0, 0, 0);
                }
            }
        }
    }

    // ---- epilogue: combine accs + bias -> ls[tok][col] ----
    #pragma unroll
    for (int mi = 0; mi < 4; ++mi) {
        const int m = PH2 ? (((7 * w) >> 1) + mi) : (4 * w + mi);
        const int col0 = m * 16 + l4 * 4;
        #pragma unroll
        for (int n = 0; n < 2; ++n) {
            bool valid = (n < ntiles);
            if (PH2) { const int ct = 2 * m + n; valid = valid && (ct >= 7 * w) && (ct < 7 * w + 7); }
            if (valid) {
                const float4 bv = *(const float4*)(bsrc + col0);
                f32x4 r;
                r[0] = accA[mi][n][0] + accB[mi][n][0] * (1.f / 2048.f) + bv.x;
                r[1] = accA[mi][n][1] + accB[mi][n][1] * (1.f / 2048.f) + bv.y;
                r[2] = accA[mi][n][2] + accB[mi][n][2] * (1.f / 2048.f) + bv.z;
                r[3] = accA[mi][n][3] + accB[mi][n][3] * (1.f / 2048.f) + bv.w;
                const int tok = n * 16 + l15;
                *(f32x4*)(ls + tok * LST + col0) = r;
            }
        }
    }
    __syncthreads();

    // ---- softmax per token ----
    float* pout = (float*)ws + (PH2 ? WS_P2 : WS_P1);
    #pragma unroll
    for (int s = 0; s < 8; ++s) {
        const int t = w * 8 + s;
        if (t >= cnt) continue;
        const float v0 = ls[t * LST + lane];
        const float v1 = ls[t * LST + 64 + lane];
        const float v2 = ls[t * LST + 128 + lane];
        const float v3 = (192 + lane < NREAL) ? ls[t * LST + 192 + lane] : -1e30f;
        float mx = fmaxf(fmaxf(v0, v1), fmaxf(v2, v3));
        #pragma unroll
        for (int k = 32; k >= 1; k >>= 1) mx = fmaxf(mx, __shfl_xor(mx, k, 64));
        float e = __expf(v0 - mx) + __expf(v1 - mx) + __expf(v2 - mx) +
                  ((192 + lane < NREAL) ? __expf(v3 - mx) : 0.f);
        #pragma unroll
        for (int k = 32; k >= 1; k >>= 1) e += __shfl_xor(e, k, 64);
        if (lane == 0) {
            const int tok = stok[t];
            const int tt  = target[tok];
            const int col = PH2 ? (tt % NPC) : (tt / NPC);
            pout[tok] = __expf(ls[t * LST + col] - mx) / e;
        }
    }
}

__global__ __launch_bounds__(256) void k_main(
    const int* __restrict__ target, const float* __restrict__ W2,
    const float* __restrict__ b2, int* __restrict__ ws)
{
    __shared__ float ls[TB * LST];
    __shared__ int stok[TB];
    const int bid = blockIdx.x;
    if (bid >= ws[WS_NCHUNK]) return;
    const int4 ce = *(const int4*)(ws + WS_CHUNK + bid * 4);
    const _Float16* w1h = (const _Float16*)(ws + WS_W1H);
    const _Float16* w1l = (const _Float16*)(ws + WS_W1L);
    const _Float16* xh  = (const _Float16*)(ws + WS_XH);
    const _Float16* xl  = (const _Float16*)(ws + WS_XL);
    if (ce.x >= 0) {
        run_chunk<true>(target, W2 + (size_t)ce.x * D * NPC, b2 + ce.x * NPC,
                        w1h, w1l, xh, xl, ws, ls, stok, ce.y, ce.z);
    } else {
        run_chunk<false>(target, nullptr, (const float*)ws + WS_B1P,
                         w1h, w1l, xh, xl, ws, ls, stok, ce.y, ce.z);
    }
}

// ---------- combine: out = p1 * p2 ----------
__global__ __launch_bounds__(256) void k_combine(const int* __restrict__ ws,
                                                 float* __restrict__ out, int ntok) {
    const int n = blockIdx.x * 256 + threadIdx.x;
    const float* p1 = (const float*)ws + WS_P1;
    const float* p2 = (const float*)ws + WS_P2;
    if (n < ntok) out[n] = p1[n] * p2[n];
}

extern "C" void kernel_launch(void* const* d_in, const int* in_sizes, int n_in,
                              void* d_out, int out_size, void* d_ws, size_t ws_size,
                              hipStream_t stream) {
    const float* x      = (const float*)d_in[0];
    const int*   target = (const int*)  d_in[1];
    const float* W1     = (const float*)d_in[2];
    const float* b1     = (const float*)d_in[3];
    const float* W2     = (const float*)d_in[4];
    const float* b2     = (const float*)d_in[5];
    float* out = (float*)d_out;
    int*   wsi = (int*)d_ws;

    const int ntok = in_sizes[1];   // 4096
    const int maxgrid = (NC + ntok / TB) + ntok / TB;          // 481
    const int pregrid = (ntok * D) / (256 * 8) + 64 + 1;       // 1089

    k_prep   <<<1, 256, 0, stream>>>(target, wsi, ntok);
    k_pre    <<<pregrid, 256, 0, stream>>>(x, W1, b1, wsi, ntok);
    k_main   <<<maxgrid, 256, 0, stream>>>(target, W2, b2, wsi);
    k_combine<<<(ntok + 255) / 256, 256, 0, stream>>>(wsi, out, ntok);
}

// Round 11
// 63.673 us; speedup vs baseline: 1.0143x; 1.0143x over previous
//
#include <hip/hip_runtime.h>
#include <cmath>

typedef _Float16 half8 __attribute__((ext_vector_type(8)));
typedef float f32x4 __attribute__((ext_vector_type(4)));

constexpr int D   = 512;
constexpr int NC  = 225;   // classes
constexpr int NPC = 224;   // outputs per class
constexpr int N1  = 256;   // padded W1 cols
constexpr int TB  = 32;    // tokens per chunk

// ws layout (int units)
constexpr int WS_NCHUNK = 0;
constexpr int WS_CHUNK  = 16;        // 962*4 ints (cls,start,cnt,colhalf)
constexpr int WS_ORDER  = 4096;      // 4096 ids grouped by class
constexpr int WS_B1P    = 8192;      // 256 floats padded b1
constexpr int WS_W1H    = 8448;      // 256*512 halves, [col][k]
constexpr int WS_W1L    = 73984;
constexpr int WS_XH     = 139520;    // 4096*512 halves
constexpr int WS_XL     = 1188096;
constexpr int WS_STAT   = 2236672;   // 4096 * 16 * float4 {m,s,e,0}; ph1 g0-7, ph2 g8-15

// ---------- prep: histogram + scans + chunk table (p2 col-halves first) + scatter ----------
__global__ __launch_bounds__(256) void k_prep(const int* __restrict__ target,
                                              int* __restrict__ ws, int ntok) {
    __shared__ int h[256], sc[256], sc2[256], cur[NC];
    const int tid = threadIdx.x;
    h[tid] = 0;
    __syncthreads();
    for (int n = tid; n < ntok; n += 256) atomicAdd(&h[target[n] / NPC], 1);
    __syncthreads();
    const int hv = h[tid];
    sc[tid] = hv; __syncthreads();
    for (int o = 1; o < 256; o <<= 1) {
        int a = (tid >= o) ? sc[tid - o] : 0;
        __syncthreads();
        sc[tid] += a;
        __syncthreads();
    }
    const int start = sc[tid] - hv;
    const int nch = (tid < NC) ? (hv + TB - 1) / TB : 0;
    sc2[tid] = nch; __syncthreads();
    for (int o = 1; o < 256; o <<= 1) {
        int a = (tid >= o) ? sc2[tid - o] : 0;
        __syncthreads();
        sc2[tid] += a;
        __syncthreads();
    }
    const int nch2 = sc2[255];
    if (tid < NC) {
        cur[tid] = start;
        const int cb = sc2[tid] - nch;
        for (int j = 0; j < nch; ++j) {
            for (int q = 0; q < 2; ++q) {
                const int e = WS_CHUNK + (((cb + j) * 2) + q) * 4;
                ws[e + 0] = tid;
                ws[e + 1] = start + j * TB;
                ws[e + 2] = min(TB, hv - j * TB);
                ws[e + 3] = q;
            }
        }
    }
    const int P1C = ntok / TB;      // 128
    if (tid < P1C) {
        for (int q = 0; q < 2; ++q) {
            const int e = WS_CHUNK + (nch2 * 2 + tid * 2 + q) * 4;
            ws[e + 0] = -1;
            ws[e + 1] = tid * TB;
            ws[e + 2] = TB;
            ws[e + 3] = q;
        }
    }
    if (tid == 0) ws[WS_NCHUNK] = nch2 * 2 + P1C * 2;
    __syncthreads();
    for (int n = tid; n < ntok; n += 256) {
        const int c = target[n] / NPC;
        const int pos = atomicAdd(&cur[c], 1);
        ws[WS_ORDER + pos] = n;
    }
}

// fp16 split: hi = RTN(v), flushed to 0 if subnormal; lo = RTN((v-hi)*2048)
__device__ __forceinline__ void f16split(float v, _Float16& h, _Float16& l) {
    _Float16 hh = (_Float16)v;
    float hf = (float)hh;
    if (fabsf(hf) < 6.104e-5f) { hh = (_Float16)0.f; hf = 0.f; }
    h = hh;
    l = (_Float16)((v - hf) * 2048.0f);
}

// ---------- pre-pass: convert x (h/l), transpose-convert W1, pad b1 ----------
__global__ __launch_bounds__(256) void k_pre(const float* __restrict__ x,
                                             const float* __restrict__ W1,
                                             const float* __restrict__ b1,
                                             int* __restrict__ ws, int ntok) {
    const int bid = blockIdx.x, tid = threadIdx.x;
    _Float16* xh  = (_Float16*)(ws + WS_XH);
    _Float16* xl  = (_Float16*)(ws + WS_XL);
    _Float16* w1h = (_Float16*)(ws + WS_W1H);
    _Float16* w1l = (_Float16*)(ws + WS_W1L);
    const int XBLK = (ntok * D) / (256 * 8);           // 1024
    if (bid < XBLK) {
        const int base = (bid * 256 + tid) * 8;
        const float4 a = *(const float4*)(x + base);
        const float4 b = *(const float4*)(x + base + 4);
        const float v[8] = {a.x, a.y, a.z, a.w, b.x, b.y, b.z, b.w};
        half8 hv, lv;
        #pragma unroll
        for (int j = 0; j < 8; ++j) {
            _Float16 hq, lq;
            f16split(v[j], hq, lq);
            hv[j] = hq; lv[j] = lq;
        }
        *(half8*)(xh + base) = hv;
        *(half8*)(xl + base) = lv;
    } else if (bid < XBLK + 64) {
        const int oi = ((bid - XBLK) * 256 + tid) * 8;  // [c][k], 8 k each
        const int c = oi >> 9, k0 = oi & 511;
        half8 hv, lv;
        #pragma unroll
        for (int j = 0; j < 8; ++j) {
            const float v = (c < NC) ? W1[(size_t)(k0 + j) * NC + c] : 0.f;
            _Float16 hq, lq;
            f16split(v, hq, lq);
            hv[j] = hq; lv[j] = lq;
        }
        *(half8*)(w1h + oi) = hv;
        *(half8*)(w1l + oi) = lv;
    } else {
        float* b1p = (float*)ws + WS_B1P;
        if (tid < N1) b1p[tid] = (tid < NC) ? b1[tid] : 0.f;
    }
}

#define LW(buf, kk)                                                              \
    do {                                                                         \
        _Pragma("unroll")                                                        \
        for (int mi = 0; mi < 2; ++mi) if (tval[mi]) {                           \
            const float* p_ = wpm[mi] + (size_t)((kk) + l4 * 8) * NPC;           \
            _Pragma("unroll")                                                    \
            for (int j = 0; j < 8; ++j) buf[mi][j] = p_[(size_t)j * NPC];        \
        }                                                                        \
    } while (0)

#define PROC(buf, kk)                                                            \
    do {                                                                         \
        half8 Bh_[2], Bl_[2];                                                    \
        _Pragma("unroll")                                                        \
        for (int n = 0; n < 2; ++n) if (n < ntiles) {                            \
            Bh_[n] = *(const half8*)(xh + xoff[n] + (kk) + l4 * 8);              \
            Bl_[n] = *(const half8*)(xl + xoff[n] + (kk) + l4 * 8);              \
        }                                                                        \
        _Pragma("unroll")                                                        \
        for (int mi = 0; mi < 2; ++mi) if (tval[mi]) {                           \
            half8 Ah_, Al_;                                                      \
            _Pragma("unroll")                                                    \
            for (int j = 0; j < 8; ++j) {                                        \
                _Float16 hq_, lq_;                                               \
                f16split(buf[mi][j], hq_, lq_);                                  \
                Ah_[j] = hq_; Al_[j] = lq_;                                      \
            }                                                                    \
            _Pragma("unroll")                                                    \
            for (int n = 0; n < 2; ++n) if (n < ntiles) {                        \
                accA[mi][n] = __builtin_amdgcn_mfma_f32_16x16x32_f16(Ah_, Bh_[n], accA[mi][n], 0, 0, 0); \
                accB[mi][n] = __builtin_amdgcn_mfma_f32_16x16x32_f16(Ah_, Bl_[n], accB[mi][n], 0, 0, 0); \
                accB[mi][n] = __builtin_amdgcn_mfma_f32_16x16x32_f16(Al_, Bh_[n], accB[mi][n], 0, 0, 0); \
            }                                                                    \
        }                                                                        \
    } while (0)

// ---------- main: per (chunk, col-half) MFMA GEMM -> per-wave softmax stats ----------
template <bool PH2>
__device__ __forceinline__ void run_chunk(
    const int* __restrict__ target, const float* __restrict__ W2c,
    const float* __restrict__ bsrc,
    const _Float16* __restrict__ w1h, const _Float16* __restrict__ w1l,
    const _Float16* __restrict__ xh, const _Float16* __restrict__ xl,
    int* __restrict__ ws, int* __restrict__ stok,
    int start, int cnt, int ch)
{
    constexpr int NREAL = PH2 ? NPC : NC;
    const int tid = threadIdx.x, w = tid >> 6, lane = tid & 63;
    const int l15 = lane & 15, l4 = lane >> 4;

    if (tid < TB)
        stok[tid] = PH2 ? ws[WS_ORDER + start + min(tid, cnt - 1)] : (start + tid);
    __syncthreads();

    const int ntiles = (cnt + 15) >> 4;
    int xoff[2];
    xoff[0] = stok[l15] * D;
    xoff[1] = stok[16 + l15] * D;

    const int mt0 = ch * 8 + w * 2;
    bool tval[2];
    tval[0] = (mt0 * 16) < NREAL;
    tval[1] = ((mt0 + 1) * 16) < NREAL;

    f32x4 accA[2][2] = {}, accB[2][2] = {};

    if constexpr (PH2) {
        const float* wpm[2];
        #pragma unroll
        for (int mi = 0; mi < 2; ++mi) {
            const int col = (mt0 + mi) * 16 + l15;
            wpm[mi] = W2c + min(col, NPC - 1);
        }
        float wra[2][8], wrb[2][8];
        LW(wra, 0);
        for (int k0 = 0; k0 < D; k0 += 64) {
            LW(wrb, k0 + 32);
            PROC(wra, k0);
            if (k0 + 64 < D) LW(wra, k0 + 64);
            PROC(wrb, k0 + 32);
        }
    } else {
        for (int k0 = 0; k0 < D; k0 += 32) {
            half8 Bh[2], Bl[2];
            #pragma unroll
            for (int n = 0; n < 2; ++n) {
                Bh[n] = *(const half8*)(xh + xoff[n] + k0 + l4 * 8);
                Bl[n] = *(const half8*)(xl + xoff[n] + k0 + l4 * 8);
            }
            #pragma unroll
            for (int mi = 0; mi < 2; ++mi) if (tval[mi]) {
                const int col = (mt0 + mi) * 16 + l15;
                const half8 Ah = *(const half8*)(w1h + (size_t)col * D + k0 + l4 * 8);
                const half8 Al = *(const half8*)(w1l + (size_t)col * D + k0 + l4 * 8);
                #pragma unroll
                for (int n = 0; n < 2; ++n) {
                    accA[mi][n] = __builtin_amdgcn_mfma_f32_16x16x32_f16(Ah, Bh[n], accA[mi][n], 0, 0, 0);
                    accB[mi][n] = __builtin_amdgcn_mfma_f32_16x16x32_f16(Ah, Bl[n], accB[mi][n], 0, 0, 0);
                    accB[mi][n] = __builtin_amdgcn_mfma_f32_16x16x32_f16(Al, Bh[n], accB[mi][n], 0, 0, 0);
                }
            }
        }
    }

    // ---- epilogue: per-wave per-token partial softmax stats {m, s, e_target} ----
    float* stat = (float*)ws + WS_STAT;
    #pragma unroll
    for (int n = 0; n < 2; ++n) {
        if (n < ntiles) {
            const int tok = stok[n * 16 + l15];
            const int tt  = target[tok];
            const int tcol = PH2 ? (tt % NPC) : (tt / NPC);
            float vals[2][4];
            float mx = -1e30f;
            #pragma unroll
            for (int mi = 0; mi < 2; ++mi) {
                const int col0 = (mt0 + mi) * 16 + l4 * 4;
                const int bcol = PH2 ? min(col0, NPC - 4) : col0;
                const float4 bv = *(const float4*)(bsrc + bcol);
                #pragma unroll
                for (int r = 0; r < 4; ++r) {
                    const float v = accA[mi][n][r] + accB[mi][n][r] * (1.f / 2048.f) + (&bv.x)[r];
                    vals[mi][r] = v;
                    if (col0 + r < NREAL) mx = fmaxf(mx, v);
                }
            }
            mx = fmaxf(mx, __shfl_xor(mx, 16, 64));
            mx = fmaxf(mx, __shfl_xor(mx, 32, 64));
            float s = 0.f, e = 0.f;
            #pragma unroll
            for (int mi = 0; mi < 2; ++mi) {
                const int col0 = (mt0 + mi) * 16 + l4 * 4;
                #pragma unroll
                for (int r = 0; r < 4; ++r) {
                    const int cr = col0 + r;
                    if (cr < NREAL) {
                        const float ex = __expf(vals[mi][r] - mx);
                        s += ex;
                        if (cr == tcol) e = ex;
                    }
                }
            }
            s += __shfl_xor(s, 16, 64); s += __shfl_xor(s, 32, 64);
            e += __shfl_xor(e, 16, 64); e += __shfl_xor(e, 32, 64);
            if (l4 == 0) {
                const int g = (PH2 ? 8 : 0) + ch * 4 + w;
                *(float4*)(stat + (size_t)tok * 64 + g * 4) = {mx, s, e, 0.f};
            }
        }
    }
}

__global__ __launch_bounds__(256, 4) void k_main(
    const int* __restrict__ target, const float* __restrict__ W2,
    const float* __restrict__ b2, int* __restrict__ ws)
{
    __shared__ int stok[TB];
    const int bid = blockIdx.x;
    if (bid >= ws[WS_NCHUNK]) return;
    const int4 ce = *(const int4*)(ws + WS_CHUNK + bid * 4);
    const _Float16* w1h = (const _Float16*)(ws + WS_W1H);
    const _Float16* w1l = (const _Float16*)(ws + WS_W1L);
    const _Float16* xh  = (const _Float16*)(ws + WS_XH);
    const _Float16* xl  = (const _Float16*)(ws + WS_XL);
    if (ce.x >= 0) {
        run_chunk<true>(target, W2 + (size_t)ce.x * D * NPC, b2 + ce.x * NPC,
                        w1h, w1l, xh, xl, ws, stok, ce.y, ce.z, ce.w);
    } else {
        run_chunk<false>(target, nullptr, (const float*)ws + WS_B1P,
                         w1h, w1l, xh, xl, ws, stok, ce.y, ce.z, ce.w);
    }
}

// ---------- combine: merge 8 stat groups per phase, out = p1*p2 ----------
__global__ __launch_bounds__(256) void k_combine(const int* __restrict__ ws,
                                                 float* __restrict__ out, int ntok) {
    const int n = blockIdx.x * 256 + threadIdx.x;
    if (n >= ntok) return;
    const float4* st = (const float4*)((const float*)ws + WS_STAT) + (size_t)n * 16;
    float p[2];
    #pragma unroll
    for (int ph = 0; ph < 2; ++ph) {
        float M = -1e30f;
        #pragma unroll
        for (int g = 0; g < 8; ++g) M = fmaxf(M, st[ph * 8 + g].x);
        float S = 0.f, E = 0.f;
        #pragma unroll
        for (int g = 0; g < 8; ++g) {
            const float4 q = st[ph * 8 + g];
            const float sc = __expf(q.x - M);
            S += q.y * sc;
            E += q.z * sc;
        }
        p[ph] = E / S;
    }
    out[n] = p[0] * p[1];
}

extern "C" void kernel_launch(void* const* d_in, const int* in_sizes, int n_in,
                              void* d_out, int out_size, void* d_ws, size_t ws_size,
                              hipStream_t stream) {
    const float* x      = (const float*)d_in[0];
    const int*   target = (const int*)  d_in[1];
    const float* W1     = (const float*)d_in[2];
    const float* b1     = (const float*)d_in[3];
    const float* W2     = (const float*)d_in[4];
    const float* b2     = (const float*)d_in[5];
    float* out = (float*)d_out;
    int*   wsi = (int*)d_ws;

    const int ntok = in_sizes[1];   // 4096
    const int maxgrid = 2 * (NC + ntok / TB) + 2 * (ntok / TB);   // 962
    const int pregrid = (ntok * D) / (256 * 8) + 64 + 1;          // 1089

    k_prep   <<<1, 256, 0, stream>>>(target, wsi, ntok);
    k_pre    <<<pregrid, 256, 0, stream>>>(x, W1, b1, wsi, ntok);
    k_main   <<<maxgrid, 256, 0, stream>>>(target, W2, b2, wsi);
    k_combine<<<(ntok + 255) / 256, 256, 0, stream>>>(wsi, out, ntok);
}

// Round 12
// 55.565 us; speedup vs baseline: 1.1624x; 1.1459x over previous
//
#include <hip/hip_runtime.h>
#include <cmath>

typedef _Float16 half8 __attribute__((ext_vector_type(8)));
typedef float f32x4 __attribute__((ext_vector_type(4)));

constexpr int D   = 512;
constexpr int NC  = 225;   // classes
constexpr int NPC = 224;   // outputs per class
constexpr int N1  = 256;   // padded W1 cols
constexpr int TB  = 32;    // tokens per chunk

// ws layout (int units)
constexpr int WS_NCHUNK = 0;
constexpr int WS_CHUNK  = 16;        // 962*4 ints (cls,start,cnt,colhalf)
constexpr int WS_ORDER  = 4096;      // 4096 ids grouped by class
constexpr int WS_B1P    = 8192;      // 256 floats padded b1
constexpr int WS_W1H    = 8448;      // 256*512 halves, [col][k]
constexpr int WS_W1L    = 73984;
constexpr int WS_XH     = 139520;    // 4096*512 halves
constexpr int WS_XL     = 1188096;
constexpr int WS_STAT   = 2236672;   // 4096 * 16 * float4 {m,s,e,0}; ph1 g0-7, ph2 g8-15

// fp16 split: hi = RTN(v), flushed to 0 if subnormal; lo = RTN((v-hi)*2048)
__device__ __forceinline__ void f16split(float v, _Float16& h, _Float16& l) {
    _Float16 hh = (_Float16)v;
    float hf = (float)hh;
    if (fabsf(hf) < 6.104e-5f) { hh = (_Float16)0.f; hf = 0.f; }
    h = hh;
    l = (_Float16)((v - hf) * 2048.0f);
}

// ---------- merged prep (block 0) + convert pre-pass (blocks 1..) ----------
__global__ __launch_bounds__(256) void k_prep_pre(
    const float* __restrict__ x, const float* __restrict__ W1,
    const float* __restrict__ b1, const int* __restrict__ target,
    int* __restrict__ ws, int ntok)
{
    const int bid = blockIdx.x, tid = threadIdx.x;
    if (bid == 0) {
        __shared__ int h[256], sc[256], sc2[256], cur[NC];
        h[tid] = 0;
        __syncthreads();
        for (int n = tid; n < ntok; n += 256) atomicAdd(&h[target[n] / NPC], 1);
        __syncthreads();
        const int hv = h[tid];
        sc[tid] = hv; __syncthreads();
        for (int o = 1; o < 256; o <<= 1) {
            int a = (tid >= o) ? sc[tid - o] : 0;
            __syncthreads();
            sc[tid] += a;
            __syncthreads();
        }
        const int start = sc[tid] - hv;
        const int nch = (tid < NC) ? (hv + TB - 1) / TB : 0;
        sc2[tid] = nch; __syncthreads();
        for (int o = 1; o < 256; o <<= 1) {
            int a = (tid >= o) ? sc2[tid - o] : 0;
            __syncthreads();
            sc2[tid] += a;
            __syncthreads();
        }
        const int nch2 = sc2[255];
        if (tid < NC) {
            cur[tid] = start;
            const int cb = sc2[tid] - nch;
            for (int j = 0; j < nch; ++j) {
                for (int q = 0; q < 2; ++q) {
                    const int e = WS_CHUNK + (((cb + j) * 2) + q) * 4;
                    ws[e + 0] = tid;
                    ws[e + 1] = start + j * TB;
                    ws[e + 2] = min(TB, hv - j * TB);
                    ws[e + 3] = q;
                }
            }
        }
        const int P1C = ntok / TB;      // 128
        if (tid < P1C) {
            for (int q = 0; q < 2; ++q) {
                const int e = WS_CHUNK + (nch2 * 2 + tid * 2 + q) * 4;
                ws[e + 0] = -1;
                ws[e + 1] = tid * TB;
                ws[e + 2] = TB;
                ws[e + 3] = q;
            }
        }
        if (tid == 0) ws[WS_NCHUNK] = nch2 * 2 + P1C * 2;
        __syncthreads();
        for (int n = tid; n < ntok; n += 256) {
            const int c = target[n] / NPC;
            const int pos = atomicAdd(&cur[c], 1);
            ws[WS_ORDER + pos] = n;
        }
        return;
    }
    const int pb = bid - 1;
    _Float16* xh  = (_Float16*)(ws + WS_XH);
    _Float16* xl  = (_Float16*)(ws + WS_XL);
    _Float16* w1h = (_Float16*)(ws + WS_W1H);
    _Float16* w1l = (_Float16*)(ws + WS_W1L);
    const int XBLK = (ntok * D) / (256 * 8);           // 1024
    if (pb < XBLK) {
        const int base = (pb * 256 + tid) * 8;
        const float4 a = *(const float4*)(x + base);
        const float4 b = *(const float4*)(x + base + 4);
        const float v[8] = {a.x, a.y, a.z, a.w, b.x, b.y, b.z, b.w};
        half8 hv, lv;
        #pragma unroll
        for (int j = 0; j < 8; ++j) {
            _Float16 hq, lq;
            f16split(v[j], hq, lq);
            hv[j] = hq; lv[j] = lq;
        }
        *(half8*)(xh + base) = hv;
        *(half8*)(xl + base) = lv;
    } else if (pb < XBLK + 64) {
        const int oi = ((pb - XBLK) * 256 + tid) * 8;  // [c][k], 8 k each
        const int c = oi >> 9, k0 = oi & 511;
        half8 hv, lv;
        #pragma unroll
        for (int j = 0; j < 8; ++j) {
            const float v = (c < NC) ? W1[(size_t)(k0 + j) * NC + c] : 0.f;
            _Float16 hq, lq;
            f16split(v, hq, lq);
            hv[j] = hq; lv[j] = lq;
        }
        *(half8*)(w1h + oi) = hv;
        *(half8*)(w1l + oi) = lv;
    } else {
        float* b1p = (float*)ws + WS_B1P;
        if (tid < N1) b1p[tid] = (tid < NC) ? b1[tid] : 0.f;
    }
}

// load 2x8 W scalars (phase 2)
#define LW(buf, kk)                                                              \
    do {                                                                         \
        _Pragma("unroll")                                                        \
        for (int mi = 0; mi < 2; ++mi) if (tval[mi]) {                           \
            const float* p_ = wpm[mi] + (size_t)((kk) + l4 * 8) * NPC;           \
            _Pragma("unroll")                                                    \
            for (int j = 0; j < 8; ++j) buf[mi][j] = p_[(size_t)j * NPC];        \
        }                                                                        \
    } while (0)

// load B fragments from pre-converted x
#define LX(bh, bl, kk)                                                           \
    do {                                                                         \
        _Pragma("unroll")                                                        \
        for (int n = 0; n < 2; ++n) if (n < ntiles) {                            \
            bh[n] = *(const half8*)(xh + xoff[n] + (kk) + l4 * 8);               \
            bl[n] = *(const half8*)(xl + xoff[n] + (kk) + l4 * 8);               \
        }                                                                        \
    } while (0)

// load A fragments from pre-converted W1
#define LA(ah, al, kk)                                                           \
    do {                                                                         \
        _Pragma("unroll")                                                        \
        for (int mi = 0; mi < 2; ++mi) if (tval[mi]) {                           \
            const int col_ = (mt0 + mi) * 16 + l15;                              \
            ah[mi] = *(const half8*)(w1h + (size_t)col_ * D + (kk) + l4 * 8);    \
            al[mi] = *(const half8*)(w1l + (size_t)col_ * D + (kk) + l4 * 8);    \
        }                                                                        \
    } while (0)

// split W regs + 12 MFMA (phase 2)
#define PROCW(buf, bh, bl)                                                       \
    do {                                                                         \
        _Pragma("unroll")                                                        \
        for (int mi = 0; mi < 2; ++mi) if (tval[mi]) {                           \
            half8 Ah_, Al_;                                                      \
            _Pragma("unroll")                                                    \
            for (int j = 0; j < 8; ++j) {                                        \
                _Float16 hq_, lq_;                                               \
                f16split(buf[mi][j], hq_, lq_);                                  \
                Ah_[j] = hq_; Al_[j] = lq_;                                      \
            }                                                                    \
            _Pragma("unroll")                                                    \
            for (int n = 0; n < 2; ++n) if (n < ntiles) {                        \
                accA[mi][n] = __builtin_amdgcn_mfma_f32_16x16x32_f16(Ah_, bh[n], accA[mi][n], 0, 0, 0); \
                accB[mi][n] = __builtin_amdgcn_mfma_f32_16x16x32_f16(Ah_, bl[n], accB[mi][n], 0, 0, 0); \
                accB[mi][n] = __builtin_amdgcn_mfma_f32_16x16x32_f16(Al_, bh[n], accB[mi][n], 0, 0, 0); \
            }                                                                    \
        }                                                                        \
    } while (0)

// 12 MFMA from preloaded A (phase 1)
#define PROCA(ah, al, bh, bl)                                                    \
    do {                                                                         \
        _Pragma("unroll")                                                        \
        for (int mi = 0; mi < 2; ++mi) if (tval[mi]) {                           \
            _Pragma("unroll")                                                    \
            for (int n = 0; n < 2; ++n) if (n < ntiles) {                        \
                accA[mi][n] = __builtin_amdgcn_mfma_f32_16x16x32_f16(ah[mi], bh[n], accA[mi][n], 0, 0, 0); \
                accB[mi][n] = __builtin_amdgcn_mfma_f32_16x16x32_f16(ah[mi], bl[n], accB[mi][n], 0, 0, 0); \
                accB[mi][n] = __builtin_amdgcn_mfma_f32_16x16x32_f16(al[mi], bh[n], accB[mi][n], 0, 0, 0); \
            }                                                                    \
        }                                                                        \
    } while (0)

// ---------- main: per (chunk, col-half) MFMA GEMM -> per-wave softmax stats ----------
template <bool PH2>
__device__ __forceinline__ void run_chunk(
    const int* __restrict__ target, const float* __restrict__ W2c,
    const float* __restrict__ bsrc,
    const _Float16* __restrict__ w1h, const _Float16* __restrict__ w1l,
    const _Float16* __restrict__ xh, const _Float16* __restrict__ xl,
    int* __restrict__ ws, int* __restrict__ stok,
    int start, int cnt, int ch)
{
    constexpr int NREAL = PH2 ? NPC : NC;
    const int tid = threadIdx.x, w = tid >> 6, lane = tid & 63;
    const int l15 = lane & 15, l4 = lane >> 4;

    if (tid < TB)
        stok[tid] = PH2 ? ws[WS_ORDER + start + min(tid, cnt - 1)] : (start + tid);
    __syncthreads();

    const int ntiles = (cnt + 15) >> 4;
    int xoff[2];
    xoff[0] = stok[l15] * D;
    xoff[1] = stok[16 + l15] * D;

    const int mt0 = ch * 8 + w * 2;
    bool tval[2];
    tval[0] = (mt0 * 16) < NREAL;
    tval[1] = ((mt0 + 1) * 16) < NREAL;

    f32x4 accA[2][2] = {}, accB[2][2] = {};

    if constexpr (PH2) {
        const float* wpm[2];
        #pragma unroll
        for (int mi = 0; mi < 2; ++mi) {
            const int col = (mt0 + mi) * 16 + l15;
            wpm[mi] = W2c + min(col, NPC - 1);
        }
        float wra[2][8], wrb[2][8];
        half8 xha[2], xla[2], xhb[2], xlb[2];
        LW(wra, 0); LX(xha, xla, 0);
        for (int k0 = 0; k0 < D; k0 += 64) {
            LW(wrb, k0 + 32); LX(xhb, xlb, k0 + 32);
            PROCW(wra, xha, xla);
            if (k0 + 64 < D) { LW(wra, k0 + 64); LX(xha, xla, k0 + 64); }
            PROCW(wrb, xhb, xlb);
        }
    } else {
        half8 aha[2], ala[2], ahb[2], alb[2];
        half8 xha[2], xla[2], xhb[2], xlb[2];
        LA(aha, ala, 0); LX(xha, xla, 0);
        for (int k0 = 0; k0 < D; k0 += 64) {
            LA(ahb, alb, k0 + 32); LX(xhb, xlb, k0 + 32);
            PROCA(aha, ala, xha, xla);
            if (k0 + 64 < D) { LA(aha, ala, k0 + 64); LX(xha, xla, k0 + 64); }
            PROCA(ahb, alb, xhb, xlb);
        }
    }

    // ---- epilogue: per-wave per-token partial softmax stats {m, s, e_target} ----
    float* stat = (float*)ws + WS_STAT;
    #pragma unroll
    for (int n = 0; n < 2; ++n) {
        if (n < ntiles) {
            const int tok = stok[n * 16 + l15];
            const int tt  = target[tok];
            const int tcol = PH2 ? (tt % NPC) : (tt / NPC);
            float vals[2][4];
            float mx = -1e30f;
            #pragma unroll
            for (int mi = 0; mi < 2; ++mi) {
                const int col0 = (mt0 + mi) * 16 + l4 * 4;
                const int bcol = PH2 ? min(col0, NPC - 4) : col0;
                const float4 bv = *(const float4*)(bsrc + bcol);
                #pragma unroll
                for (int r = 0; r < 4; ++r) {
                    const float v = accA[mi][n][r] + accB[mi][n][r] * (1.f / 2048.f) + (&bv.x)[r];
                    vals[mi][r] = v;
                    if (col0 + r < NREAL) mx = fmaxf(mx, v);
                }
            }
            mx = fmaxf(mx, __shfl_xor(mx, 16, 64));
            mx = fmaxf(mx, __shfl_xor(mx, 32, 64));
            float s = 0.f, e = 0.f;
            #pragma unroll
            for (int mi = 0; mi < 2; ++mi) {
                const int col0 = (mt0 + mi) * 16 + l4 * 4;
                #pragma unroll
                for (int r = 0; r < 4; ++r) {
                    const int cr = col0 + r;
                    if (cr < NREAL) {
                        const float ex = __expf(vals[mi][r] - mx);
                        s += ex;
                        if (cr == tcol) e = ex;
                    }
                }
            }
            s += __shfl_xor(s, 16, 64); s += __shfl_xor(s, 32, 64);
            e += __shfl_xor(e, 16, 64); e += __shfl_xor(e, 32, 64);
            if (l4 == 0) {
                const int g = (PH2 ? 8 : 0) + ch * 4 + w;
                *(float4*)(stat + (size_t)tok * 64 + g * 4) = {mx, s, e, 0.f};
            }
        }
    }
}

__global__ __launch_bounds__(256, 4) void k_main(
    const int* __restrict__ target, const float* __restrict__ W2,
    const float* __restrict__ b2, int* __restrict__ ws)
{
    __shared__ int stok[TB];
    const int bid = blockIdx.x;
    if (bid >= ws[WS_NCHUNK]) return;
    const int4 ce = *(const int4*)(ws + WS_CHUNK + bid * 4);
    const _Float16* w1h = (const _Float16*)(ws + WS_W1H);
    const _Float16* w1l = (const _Float16*)(ws + WS_W1L);
    const _Float16* xh  = (const _Float16*)(ws + WS_XH);
    const _Float16* xl  = (const _Float16*)(ws + WS_XL);
    if (ce.x >= 0) {
        run_chunk<true>(target, W2 + (size_t)ce.x * D * NPC, b2 + ce.x * NPC,
                        w1h, w1l, xh, xl, ws, stok, ce.y, ce.z, ce.w);
    } else {
        run_chunk<false>(target, nullptr, (const float*)ws + WS_B1P,
                         w1h, w1l, xh, xl, ws, stok, ce.y, ce.z, ce.w);
    }
}

// ---------- combine: merge 8 stat groups per phase, out = p1*p2 ----------
__global__ __launch_bounds__(256) void k_combine(const int* __restrict__ ws,
                                                 float* __restrict__ out, int ntok) {
    const int n = blockIdx.x * 256 + threadIdx.x;
    if (n >= ntok) return;
    const float4* st = (const float4*)((const float*)ws + WS_STAT) + (size_t)n * 16;
    float p[2];
    #pragma unroll
    for (int ph = 0; ph < 2; ++ph) {
        float M = -1e30f;
        #pragma unroll
        for (int g = 0; g < 8; ++g) M = fmaxf(M, st[ph * 8 + g].x);
        float S = 0.f, E = 0.f;
        #pragma unroll
        for (int g = 0; g < 8; ++g) {
            const float4 q = st[ph * 8 + g];
            const float sc = __expf(q.x - M);
            S += q.y * sc;
            E += q.z * sc;
        }
        p[ph] = E / S;
    }
    out[n] = p[0] * p[1];
}

extern "C" void kernel_launch(void* const* d_in, const int* in_sizes, int n_in,
                              void* d_out, int out_size, void* d_ws, size_t ws_size,
                              hipStream_t stream) {
    const float* x      = (const float*)d_in[0];
    const int*   target = (const int*)  d_in[1];
    const float* W1     = (const float*)d_in[2];
    const float* b1     = (const float*)d_in[3];
    const float* W2     = (const float*)d_in[4];
    const float* b2     = (const float*)d_in[5];
    float* out = (float*)d_out;
    int*   wsi = (int*)d_ws;

    const int ntok = in_sizes[1];   // 4096
    const int maxgrid = 2 * (NC + ntok / TB) + 2 * (ntok / TB);     // 962
    const int pregrid = 1 + (ntok * D) / (256 * 8) + 64 + 1;        // 1090

    k_prep_pre<<<pregrid, 256, 0, stream>>>(x, W1, b1, target, wsi, ntok);
    k_main    <<<maxgrid, 256, 0, stream>>>(target, W2, b2, wsi);
    k_combine <<<(ntok + 255) / 256, 256, 0, stream>>>(wsi, out, ntok);
}